// Round 13
// baseline (1902.996 us; speedup 1.0000x reference)
//
#include <hip/hip_runtime.h>

// MyRnn: 2-layer SimpleRNN, B=1024 T=80 U=1024 E=100. f32 I/O, f16 MFMA compute.
// v11: chunk-loop restructure. Evidence: v7/v10 flat at ~21us/iter regardless of
// traffic (v10: +16MB/iter FETCH, 0 time delta) -> memory-side models dead.
// Invariant = 32 barrier-rounds/iter at 2 waves/SIMD with 1-deep prefetch
// (exposed ~400cy/chunk) + 6300 conflict-cyc/CU/iter. v8 fixed the latter two
// but DOUBLED barriers -> net loss. v11 fixes all three at CONSTANT barrier
// count: 512-thread blocks (8 waves -> 4 waves/SIMD), KC=64 with 4 LDS buffers,
// SINGLE barrier/chunk (vmcnt(4) -> barrier -> issue(c+3) -> compute(c); the
// 4th buffer's last reader finished >=1 barrier ago so no trailing barrier),
// 3-chunk issue distance (~700cy >= bypass latency), v8's conflict-free
// staging geometry. Mapping/coherence/gsync = v7 verbatim.

typedef _Float16 h8v __attribute__((ext_vector_type(8)));
typedef float    f4v __attribute__((ext_vector_type(4)));
typedef unsigned int u4v __attribute__((ext_vector_type(4)));

#define UNITS 1024
#define SEQ   80
#define EMBD  100
#define EPAD  128
#define KC    64
#define GRID  512

__device__ __forceinline__ float tanh_fast(float x) {
    x = fminf(15.f, fmaxf(-15.f, x));   // also scrubs NaN
    float e = __expf(2.f * x);
    return (e - 1.f) / (e + 1.f);
}

// cacheable global->LDS (weights, EMBP): L1/L2-resident across iterations
__device__ __forceinline__ void gl_lds16_c(const _Float16* g, _Float16* l) {
    __builtin_amdgcn_global_load_lds(
        (const __attribute__((address_space(1))) void*)g,
        (__attribute__((address_space(3))) void*)l, 16, 0, 0);
}
// device-coherent bypass global->LDS (h-state): aux = sc0|sc1 = 0x11
__device__ __forceinline__ void gl_lds16_v(const _Float16* g, _Float16* l) {
    __builtin_amdgcn_global_load_lds(
        (const __attribute__((address_space(1))) void*)g,
        (__attribute__((address_space(3))) void*)l, 16, 0, 0x11);
}
// write-through device-coherent 2B store (h-state)
__device__ __forceinline__ void st2_wt(_Float16* p, float v) {
    _Float16 h = (_Float16)v;
    unsigned int uv = (unsigned int)__builtin_bit_cast(unsigned short, h);
    asm volatile("global_store_short %0, %1, off sc0 sc1" :: "v"(p), "v"(uv) : "memory");
}
// device-coherent 16B load (tail h read)
__device__ __forceinline__ u4v ld16_v(const void* p) {
    u4v r;
    asm volatile("global_load_dwordx4 %0, %1, off sc0 sc1\n\ts_waitcnt vmcnt(0)"
                 : "=v"(r) : "v"(p) : "memory");
    return r;
}
// write-through 16B store (h zero-init must land at coherent point)
__device__ __forceinline__ void st16_wt(void* p, u4v v) {
    asm volatile("global_store_dwordx4 %0, %1, off sc0 sc1" :: "v"(p), "v"(v) : "memory");
}

// embp[r][k] = k<100 ? (f16)emb[r][k] : 0   (10000 x 128)
__global__ void embp_kernel(const float* __restrict__ emb, _Float16* __restrict__ embp) {
    int r = blockIdx.x, k = threadIdx.x;
    embp[r * EPAD + k] = (k < EMBD) ? (_Float16)emb[r * EMBD + k] : (_Float16)0.f;
}

// wt[n][kp] = kp<K ? (f16)w[kp][n] : 0 ; wt row stride Kpad. block (32,8).
__global__ void tpad_kernel(const float* __restrict__ w, _Float16* __restrict__ wt,
                            int K, int Kpad, int N) {
    __shared__ float t[32][33];
    int k0 = blockIdx.x * 32, n0 = blockIdx.y * 32;
    int tx = threadIdx.x, ty = threadIdx.y;
    for (int i = ty; i < 32; i += 8) {
        int k = k0 + i;
        t[i][tx] = (k < K) ? w[(size_t)k * N + n0 + tx] : 0.f;
    }
    __syncthreads();
    for (int i = ty; i < 32; i += 8)
        wt[(size_t)(n0 + i) * Kpad + k0 + tx] = (_Float16)t[tx][i];
}

// blocks 0..2047: zero 8 MB H region WRITE-THROUGH; block 2048: zero sync words
__global__ void zero_kernel(char* __restrict__ p, unsigned* __restrict__ sync) {
    if (blockIdx.x == 2048) {
        if (threadIdx.x < 512)
            __hip_atomic_store(sync + threadIdx.x, 0u, __ATOMIC_RELAXED,
                               __HIP_MEMORY_SCOPE_AGENT);
        return;
    }
    u4v z = {0u, 0u, 0u, 0u};
    st16_wt(p + ((size_t)blockIdx.x * 256 + threadIdx.x) * 16, z);
}

// sync layout (u32 words): xcnt[g] at [g*16], root at [128], epoch[g] at [144+g*16]
struct PArgs {
    const int* x;            // [1024][80]
    const _Float16* EMBP;    // [10000][128]
    const _Float16* W0XT;    // [1024][128]
    const _Float16* W0HT;    // [1024][1024]
    const _Float16* W1XT;    // [1024][1024]
    const _Float16* W1HT;    // [1024][1024]
    const float* b0; const float* b1;
    _Float16* H00; _Float16* H01;   // h0 ping-pong
    _Float16* H10; _Float16* H11;   // h1 ping-pong
    const float* wout; const float* bout; float* out;
    unsigned* sync;
};

// z = 0 (blocks 0..255):   l1 task — h1_{it-1} = tanh(h0_{it-1}@W1x + h1_{it-2}@W1h + b1), it in [1,80]
// z = 1 (blocks 256..511): l0 task — h0_{it}   = tanh(emb[x[:,it]]@W0x + h0_{it-1}@W0h + b0), it in [0,79]
__launch_bounds__(512, 4)
__global__ void rnn_kernel(PArgs P) {
    __shared__ _Float16 As[4][64 * KC];   // 4 x 8 KB, XOR-8 swizzled
    __shared__ _Float16 Bs[4][64 * KC];   // 4 x 8 KB  (64 KB total -> 2 blocks/CU)

    const int tid  = threadIdx.x;
    const int lane = tid & 63, w = tid >> 6;    // 8 waves
    const int wm = w >> 2, wn = w & 3;          // wave tile 32x16 in 2x4 grid
    const int quad = lane >> 4, l16 = lane & 15;

    const int b   = blockIdx.x;          // 0..511
    const int z   = b >> 8;              // task select
    const int bid = b & 255;
    // XCD-aware 4x8 tile clustering (v7 verbatim; perf heuristic only)
    const int xcd = bid & 7, loc = bid >> 3;
    const int col0 = (((xcd & 3) << 2) | (loc & 3)) << 6;
    const int row0 = (((xcd >> 2) << 3) | (loc >> 2)) << 6;

    // staging geometry (KC=64, 8 waves): 1 A-instr + 1 B-instr per wave per
    // chunk; wave w covers rows [w*8, w*8+8), lane l -> row r = w*8 + (l>>3),
    // stored 16B-unit u' = l&7, logical u = u' ^ (r&7)  (v8 geometry, 0 confl.)
    const int rA   = w * 8 + (lane >> 3);
    const int rrA  = w * 512;                      // LDS base (halves)
    const int gofA = 8 * ((lane & 7) ^ (rA & 7));  // swizzled k-offset (halves)

    // iteration-invariant B (weight) panel pointers — cacheable, L2-hot
    const _Float16* B0T = z ? P.W0XT : P.W1XT;
    const _Float16* B1T = z ? P.W0HT : P.W1HT;
    const int  ldb0  = z ? EPAD : UNITS;
    const int  nch0_ = z ? 2 : 16;             // KC=64 chunks in source 0
    const int  nch_  = nch0_ + 16;             // + source 1 (K=1024)
    const float* bias = z ? P.b0 : P.b1;
    const _Float16* b0p = B0T + (size_t)(col0 + rA) * ldb0  + gofA;
    const _Float16* b1p = B1T + (size_t)(col0 + rA) * UNITS + gofA;

    _Float16* Hh0[2] = { P.H00, P.H01 };
    _Float16* Hh1[2] = { P.H10, P.H11 };

    unsigned* xcnt  = P.sync + (b & 7) * 16;
    unsigned* root  = P.sync + 128;
    unsigned* epoch = P.sync + 144 + (b & 7) * 16;

    for (int it = 0; it <= SEQ; ++it) {
        const int p = it & 1;
        const bool active = z ? (it < SEQ) : (it >= 1);
        if (active) {
            const _Float16* a0p; const _Float16* a1p;
            _Float16* outp;
            if (z) {                      // l0: out h0_it
                outp = Hh0[p];
                int xi = P.x[(size_t)(row0 + rA) * SEQ + it];
                a0p = P.EMBP + (size_t)xi * EPAD + gofA;
                a1p = Hh0[p ^ 1] + (size_t)(row0 + rA) * UNITS + gofA;
            } else {                      // l1: out h1_{it-1}
                outp = Hh1[p ^ 1];
                a0p = Hh0[p ^ 1] + (size_t)(row0 + rA) * UNITS + gofA;
                a1p = Hh1[p]     + (size_t)(row0 + rA) * UNITS + gofA;
            }

            f4v acc[2] = {};

            // 2 loads/wave/chunk. A-side: h panels bypass (l1 both, l0 src1);
            // EMBP cacheable. B-side (weights) always cacheable.
            auto issue = [&](int c) {
                const int buf = c & 3;
                const _Float16* ap; const _Float16* bp; bool byp;
                if (c < nch0_) { ap = a0p + c * KC; bp = b0p + c * KC; byp = (z == 0); }
                else { int cc = c - nch0_; ap = a1p + cc * KC; bp = b1p + cc * KC; byp = true; }
                if (byp) gl_lds16_v(ap, &As[buf][0] + rrA);
                else     gl_lds16_c(ap, &As[buf][0] + rrA);
                gl_lds16_c(bp, &Bs[buf][0] + rrA);
            };

            issue(0); issue(1); issue(2);          // 3-deep prologue (6 loads/wave)
            for (int c = 0; c < nch_; ++c) {
                const int cur = c & 3;
                // outstanding at top of c: chunks c..min(c+2,nch-1); wait c done
                const int rem = nch_ - 1 - c;
                if (rem >= 2)      asm volatile("s_waitcnt vmcnt(4)" ::: "memory");
                else if (rem == 1) asm volatile("s_waitcnt vmcnt(2)" ::: "memory");
                else               asm volatile("s_waitcnt vmcnt(0)" ::: "memory");
                __builtin_amdgcn_s_barrier();      // ONLY barrier this chunk:
                __builtin_amdgcn_sched_barrier(0); // certifies compute c-1 done
                if (c + 3 < nch_) issue(c + 3);    // buf[(c+3)&3]=buf[(c-1)&3]: safe
                #pragma unroll
                for (int kk = 0; kk < 2; ++kk) {   // KC=64 -> 2 MFMA K-steps
                    int us = 8 * ((kk * 4 + quad) ^ (l16 & 7));
                    h8v af[2], bf;
                    #pragma unroll
                    for (int i = 0; i < 2; ++i)
                        af[i] = *(const h8v*)(&As[cur][0] + (wm * 32 + i * 16 + l16) * KC + us);
                    bf = *(const h8v*)(&Bs[cur][0] + (wn * 16 + l16) * KC + us);
                    #pragma unroll
                    for (int i = 0; i < 2; ++i)
                        acc[i] = __builtin_amdgcn_mfma_f32_16x16x32_f16(
                            af[i], bf, acc[i], 0, 0, 0);
                }
                __builtin_amdgcn_sched_barrier(0); // no ds_read sinks past next barrier
            }

            // epilogue: write-through device-coherent h stores
            {
                int cc = col0 + wn * 16 + l16;
                float bv = bias[cc];
                #pragma unroll
                for (int i = 0; i < 2; ++i) {
                    int r = row0 + wm * 32 + i * 16 + quad * 4;
                    #pragma unroll
                    for (int g = 0; g < 4; ++g)
                        st2_wt(outp + (size_t)(r + g) * UNITS + cc,
                               tanh_fast(acc[i][g] + bv));
                }
            }
        }

        // ---- grid barrier: relaxed atomics only (no inv, no wbl2) ----
        const unsigned tgt = (unsigned)(it + 1);
        __syncthreads();                 // drains vmcnt(0): WT stores coherent-visible
        if (tid == 0) {
            unsigned r = __hip_atomic_fetch_add(xcnt, 1u, __ATOMIC_RELAXED,
                                                __HIP_MEMORY_SCOPE_AGENT);
            if ((r & 63u) == 63u)        // group complete -> promote to root
                __hip_atomic_fetch_add(root, 1u, __ATOMIC_RELAXED,
                                       __HIP_MEMORY_SCOPE_AGENT);
            if (b == 0) {
                while (__hip_atomic_load(root, __ATOMIC_RELAXED,
                                         __HIP_MEMORY_SCOPE_AGENT) < 8u * tgt)
                    __builtin_amdgcn_s_sleep(2);
                #pragma unroll
                for (int xx = 0; xx < 8; ++xx)
                    __hip_atomic_store(P.sync + 144 + xx * 16, tgt, __ATOMIC_RELAXED,
                                       __HIP_MEMORY_SCOPE_AGENT);
            }
            while (__hip_atomic_load(epoch, __ATOMIC_RELAXED,
                                     __HIP_MEMORY_SCOPE_AGENT) < tgt)
                __builtin_amdgcn_s_sleep(2);
        }
        __syncthreads();
    }

    // tail: out[b] = sigmoid(h1_79[b] . wout + bout); h1_79 = H11 (bypass reads)
    if (b < 256 && w < 4) {
        int row = b * 4 + w;
        const _Float16* hr = P.H11 + (size_t)row * UNITS;
        u4v d0 = ld16_v(hr + lane * 16);
        u4v d1 = ld16_v(hr + lane * 16 + 8);
        float sacc = 0.f;
        #pragma unroll
        for (int i = 0; i < 4; ++i) {
            unsigned w0 = d0[i], w1 = d1[i];
            _Float16 h0 = __builtin_bit_cast(_Float16, (unsigned short)(w0 & 0xffffu));
            _Float16 h1 = __builtin_bit_cast(_Float16, (unsigned short)(w0 >> 16));
            _Float16 h2 = __builtin_bit_cast(_Float16, (unsigned short)(w1 & 0xffffu));
            _Float16 h3 = __builtin_bit_cast(_Float16, (unsigned short)(w1 >> 16));
            sacc += (float)h0 * P.wout[lane * 16 + 2 * i + 0];
            sacc += (float)h1 * P.wout[lane * 16 + 2 * i + 1];
            sacc += (float)h2 * P.wout[lane * 16 + 8 + 2 * i + 0];
            sacc += (float)h3 * P.wout[lane * 16 + 8 + 2 * i + 1];
        }
        #pragma unroll
        for (int off = 32; off; off >>= 1) sacc += __shfl_down(sacc, off);
        if (lane == 0)
            P.out[row] = 1.f / (1.f + __expf(-(sacc + P.bout[0])));
    }
}

extern "C" void kernel_launch(void* const* d_in, const int* in_sizes, int n_in,
                              void* d_out, int out_size, void* d_ws, size_t ws_size,
                              hipStream_t stream) {
    const int*   x    = (const int*)d_in[0];
    const float* emb  = (const float*)d_in[1];
    const float* W0x  = (const float*)d_in[2];
    const float* W0h  = (const float*)d_in[3];
    const float* b0   = (const float*)d_in[4];
    const float* W1x  = (const float*)d_in[5];
    const float* W1h  = (const float*)d_in[6];
    const float* b1   = (const float*)d_in[7];
    const float* Wout = (const float*)d_in[8];
    const float* bout = (const float*)d_in[9];
    float* out = (float*)d_out;

    char* ws = (char*)d_ws;
    _Float16* EMBP = (_Float16*)ws;                          // 10000*128*2 = 2,560,000 B
    _Float16* W0XT = (_Float16*)(ws + 2560000);              // [1024][128]  = 262,144 B
    _Float16* W0HT = W0XT + 1024 * EPAD;                     // [1024][1024] x3
    _Float16* W1XT = W0HT + 1024 * 1024;
    _Float16* W1HT = W1XT + 1024 * 1024;
    _Float16* Hbuf = W1HT + 1024 * 1024;                     // 4 x 2 MB
    _Float16* H00 = Hbuf;
    _Float16* H01 = Hbuf + 1024 * 1024;
    _Float16* H10 = Hbuf + 2 * 1024 * 1024;
    _Float16* H11 = Hbuf + 3 * 1024 * 1024;
    unsigned* SYNC = (unsigned*)((char*)(Hbuf + 4 * 1024 * 1024));

    embp_kernel<<<10000, EPAD, 0, stream>>>(emb, EMBP);
    tpad_kernel<<<dim3(4, 32),  dim3(32, 8), 0, stream>>>(W0x, W0XT, EMBD, EPAD, UNITS);
    tpad_kernel<<<dim3(32, 32), dim3(32, 8), 0, stream>>>(W0h, W0HT, UNITS, UNITS, UNITS);
    tpad_kernel<<<dim3(32, 32), dim3(32, 8), 0, stream>>>(W1x, W1XT, UNITS, UNITS, UNITS);
    tpad_kernel<<<dim3(32, 32), dim3(32, 8), 0, stream>>>(W1h, W1HT, UNITS, UNITS, UNITS);
    zero_kernel<<<2049, 256, 0, stream>>>((char*)Hbuf, SYNC); // WT zeros + sync words

    PArgs P;
    P.x = x; P.EMBP = EMBP;
    P.W0XT = W0XT; P.W0HT = W0HT; P.W1XT = W1XT; P.W1HT = W1HT;
    P.b0 = b0; P.b1 = b1;
    P.H00 = H00; P.H01 = H01; P.H10 = H10; P.H11 = H11;
    P.wout = Wout; P.bout = bout; P.out = out;
    P.sync = SYNC;
    rnn_kernel<<<GRID, 512, 0, stream>>>(P);
}